// Round 3
// baseline (622.335 us; speedup 1.0000x reference)
//
#include <hip/hip_runtime.h>
#include <hip/hip_bf16.h>
#include <stdint.h>

// Problem constants (from setup_inputs): B=8192, D_in=1024, H=2048
#define B_DIM 8192
#define D_IN  1024
#define H_DIM 2048
#define K_DIM (D_IN + H_DIM)   // 3072: A = [x | u], Wc = [win | wr] (virtual concat)

#define CV_CONST  (1.0f - 1.0f/150.0f)   // (1-ALPHA_V)
#define CUV_CONST (10.0f/150.0f)         // ALPHA_V*M
#define CU_CONST  0.9f                   // (1-ALPHA_U)
#define AU_CONST  0.1f                   // ALPHA_U

typedef __attribute__((ext_vector_type(8))) short short8;   // 8 bf16 = 4 VGPRs
typedef __attribute__((ext_vector_type(4))) float floatx4;

// Packed fp32x2 -> bf16x2. gfx950 has v_cvt_pk_bf16_f32 (1 VALU op per pair).
#if defined(__has_builtin)
#if __has_builtin(__builtin_amdgcn_cvt_pk_bf16_f32)
#define HAVE_CVT_PK_BF16 1
#endif
#endif

__device__ __forceinline__ unsigned pk2bf(float a, float b) {
#ifdef HAVE_CVT_PK_BF16
    typedef __attribute__((ext_vector_type(2))) __bf16 bf16x2;
    bf16x2 v = __builtin_amdgcn_cvt_pk_bf16_f32(a, b);
    union { bf16x2 v; unsigned u; } cv; cv.v = v;
    return cv.u;
#else
    union { float f; unsigned u; } ua, ub; ua.f = a; ub.f = b;
    unsigned ra = ua.u + 0x7fffu + ((ua.u >> 16) & 1u);
    unsigned rb = ub.u + 0x7fffu + ((ub.u >> 16) & 1u);
    return (ra >> 16) | (rb & 0xffff0000u);
#endif
}

// ---------------------------------------------------------------------------
// Single fused kernel: C = [x|u](8192x3072) * [win|wr](2048x3072)^T with
// in-kernel fp32->bf16 conversion during staging (no pack pre-pass), fp32
// accumulate, epilogue computes v_new/u_new with float4 I/O.
//
// K-loop pipeline per iter: [prefetch fp32 regs k+1] -> ds_read frags -> 16 MFMA
//   -> barrier -> cvt+ds_write k+1 -> barrier.  Loads are in flight across the
// whole MFMA phase instead of being drained at the barrier with zero distance.
// ---------------------------------------------------------------------------
#define ES_STRIDE 68
#define ES_REGION (16 * ES_STRIDE)          // 1088 floats
#define SMEM_BYTES (8 * ES_REGION * 4)      // 34816 B >= As+Bs (16384 B)

__global__ __launch_bounds__(256, 3)
void gemm_fused(const float* __restrict__ x,     // [8192][1024]
                const float* __restrict__ u_in,  // [8192][2048]
                const float* __restrict__ v_in,  // [8192][2048]
                const float* __restrict__ win,   // [2048][1024]
                const float* __restrict__ wr,    // [2048][2048]
                const float* __restrict__ bias,  // [2048]
                float* __restrict__ out)         // [u_new | v_new]
{
    __shared__ __align__(16) unsigned char smem_raw[SMEM_BYTES];
    unsigned short* As = (unsigned short*)smem_raw;        // 128x32 bf16 = 8 KB
    unsigned short* Bs = As + 128 * 32;                    // 8 KB
    float* Esf = (float*)smem_raw;                         // epilogue scratch (aliases)

    const int tid  = threadIdx.x;
    const int wave = tid >> 6;
    const int lane = tid & 63;

    // XCD swizzle: consecutive blockIdx round-robin XCDs; give each XCD a
    // contiguous band of bm rows so co-resident blocks share A rows in L2.
    const int bid = blockIdx.x;
    const int wid = ((bid & 7) << 7) | (bid >> 3);
    const int bm = wid >> 4;     // 0..63
    const int bn = wid & 15;     // 0..15

    // --- staging addressing: each wave stages rows [wave*32, wave*32+32) of
    // both A and B tiles; lane covers 1 row x 16 cols (2 k-groups of 8).
    const int srow = lane >> 1;              // 0..31
    const int half = lane & 1;               // which 16-col half
    const int trow = wave * 32 + srow;       // tile row 0..127
    const int cb   = half * 16;              // col base in BK=32
    const int g0   = half * 2;               // first k-group
    const int rr   = (trow & 15) >> 1;       // swizzle rotation for this row
    const int s0   = (g0 + rr) & 3;          // LDS slot of k-group g0
    const int s1   = (g0 + 1 + rr) & 3;      // LDS slot of k-group g0+1
    unsigned short* AsW0 = As + trow * 32 + s0 * 8;
    unsigned short* AsW1 = As + trow * 32 + s1 * 8;
    unsigned short* BsW0 = Bs + trow * 32 + s0 * 8;
    unsigned short* BsW1 = Bs + trow * 32 + s1 * 8;

    // Virtual concat sources: k<1024 -> x/win (stride 1024); else u/wr (2048).
    const float* aBaseX = x    + (size_t)(bm * 128 + trow) * D_IN  + cb;
    const float* aBaseU = u_in + (size_t)(bm * 128 + trow) * H_DIM + cb - D_IN;
    const float* bBaseW = win  + (size_t)(bn * 128 + trow) * D_IN  + cb;
    const float* bBaseR = wr   + (size_t)(bn * 128 + trow) * H_DIM + cb - D_IN;

    // --- compute-side fragment addressing (matches swizzle)
    const int wm = (wave >> 1) * 64;
    const int wn = (wave & 1) * 64;
    const int frow = lane & 15;
    const int g    = lane >> 4;                       // k-group 0..3
    const int swz  = ((g + (frow >> 1)) & 3) * 8;     // swizzled element offset

    float4 pa[4], pb[4];   // fp32 prefetch regs: 16 A floats + 16 B floats

    auto loadAB = [&](int k0) {
        const float* ap = (k0 < D_IN) ? (aBaseX + k0) : (aBaseU + k0);
        const float* bp = (k0 < D_IN) ? (bBaseW + k0) : (bBaseR + k0);
#pragma unroll
        for (int t = 0; t < 4; t++) {
            pa[t] = *(const float4*)(ap + 4 * t);
            pb[t] = *(const float4*)(bp + 4 * t);
        }
    };
    auto stageAB = [&]() {
        uint4 wa0 = { pk2bf(pa[0].x, pa[0].y), pk2bf(pa[0].z, pa[0].w),
                      pk2bf(pa[1].x, pa[1].y), pk2bf(pa[1].z, pa[1].w) };
        uint4 wa1 = { pk2bf(pa[2].x, pa[2].y), pk2bf(pa[2].z, pa[2].w),
                      pk2bf(pa[3].x, pa[3].y), pk2bf(pa[3].z, pa[3].w) };
        uint4 wb0 = { pk2bf(pb[0].x, pb[0].y), pk2bf(pb[0].z, pb[0].w),
                      pk2bf(pb[1].x, pb[1].y), pk2bf(pb[1].z, pb[1].w) };
        uint4 wb1 = { pk2bf(pb[2].x, pb[2].y), pk2bf(pb[2].z, pb[2].w),
                      pk2bf(pb[3].x, pb[3].y), pk2bf(pb[3].z, pb[3].w) };
        *(uint4*)AsW0 = wa0;
        *(uint4*)AsW1 = wa1;
        *(uint4*)BsW0 = wb0;
        *(uint4*)BsW1 = wb1;
    };

    floatx4 acc[4][4] = {};

    loadAB(0);
    stageAB();
    __syncthreads();

    for (int k0 = 0; k0 < K_DIM; ) {
        const int kn = k0 + 32;
        if (kn < K_DIM) loadAB(kn);       // in flight across the MFMA phase

        short8 af[4], bfr[4];
#pragma unroll
        for (int i = 0; i < 4; i++)
            af[i] = *(const short8*)&As[(wm + i * 16 + frow) * 32 + swz];
#pragma unroll
        for (int j = 0; j < 4; j++)
            bfr[j] = *(const short8*)&Bs[(wn + j * 16 + frow) * 32 + swz];

#pragma unroll
        for (int i = 0; i < 4; i++)
#pragma unroll
            for (int j = 0; j < 4; j++)
                acc[i][j] = __builtin_amdgcn_mfma_f32_16x16x32_bf16(
                    af[i], bfr[j], acc[i][j], 0, 0, 0);

        k0 = kn;
        if (k0 >= K_DIM) break;
        __syncthreads();                  // all waves done reading As/Bs
        stageAB();                        // cvt + ds_write tile k0
        __syncthreads();                  // writes visible
    }

    __syncthreads();   // protect Es aliasing of As/Bs

    // --- epilogue: transpose each 16x64 i-slice through LDS, then float4 I/O.
    // C/D layout: col = lane&15, row = (lane>>4)*4 + reg.
    const int q   = lane >> 4;
    const int c16 = lane & 15;
    const int rbase = q * 4;
    const int colg = bn * 128 + wn + c16 * 4;
    const float4 b4 = *(const float4*)&bias[colg];
    const size_t outV = (size_t)B_DIM * H_DIM;

#pragma unroll
    for (int i = 0; i < 4; i++) {
        float* Es = Esf + (wave * 2 + (i & 1)) * ES_REGION;
#pragma unroll
        for (int j = 0; j < 4; j++)
#pragma unroll
            for (int r = 0; r < 4; r++)
                Es[(rbase + r) * ES_STRIDE + j * 16 + c16] = acc[i][j][r];
#pragma unroll
        for (int rg = 0; rg < 4; rg++) {
            const int rloc = rg * 4 + q;
            const float4 a4 = *(const float4*)&Es[rloc * ES_STRIDE + c16 * 4];
            const size_t idx = (size_t)(bm * 128 + wm + i * 16 + rloc) * H_DIM + colg;
            const float4 u4 = *(const float4*)&u_in[idx];
            const float4 v4 = *(const float4*)&v_in[idx];
            float4 vn, un;
            vn.x = fmaxf(CV_CONST * v4.x + CUV_CONST * u4.x, 0.0f);
            vn.y = fmaxf(CV_CONST * v4.y + CUV_CONST * u4.y, 0.0f);
            vn.z = fmaxf(CV_CONST * v4.z + CUV_CONST * u4.z, 0.0f);
            vn.w = fmaxf(CV_CONST * v4.w + CUV_CONST * u4.w, 0.0f);
            un.x = fmaxf(CU_CONST * u4.x + AU_CONST * (a4.x + b4.x - vn.x), 0.0f);
            un.y = fmaxf(CU_CONST * u4.y + AU_CONST * (a4.y + b4.y - vn.y), 0.0f);
            un.z = fmaxf(CU_CONST * u4.z + AU_CONST * (a4.z + b4.z - vn.z), 0.0f);
            un.w = fmaxf(CU_CONST * u4.w + AU_CONST * (a4.w + b4.w - vn.w), 0.0f);
            *(float4*)&out[idx]        = un;
            *(float4*)&out[outV + idx] = vn;
        }
    }
}

// ---------------------------------------------------------------------------
extern "C" void kernel_launch(void* const* d_in, const int* in_sizes, int n_in,
                              void* d_out, int out_size, void* d_ws, size_t ws_size,
                              hipStream_t stream) {
    const float* x    = (const float*)d_in[0];
    const float* u    = (const float*)d_in[1];
    const float* v    = (const float*)d_in[2];
    const float* win  = (const float*)d_in[3];
    const float* wr   = (const float*)d_in[4];
    const float* bias = (const float*)d_in[5];
    float* out = (float*)d_out;

    gemm_fused<<<1024, 256, 0, stream>>>(x, u, v, win, wr, bias, out);
}

// Round 4
// 408.342 us; speedup vs baseline: 1.5241x; 1.5241x over previous
//
#include <hip/hip_runtime.h>
#include <hip/hip_bf16.h>
#include <stdint.h>

// Problem constants (from setup_inputs): B=8192, D_in=1024, H=2048
#define B_DIM 8192
#define D_IN  1024
#define H_DIM 2048
#define K_DIM (D_IN + H_DIM)   // 3072: A = [x | u], Wc = [win | wr]

#define CV_CONST  (1.0f - 1.0f/150.0f)   // (1-ALPHA_V)
#define CUV_CONST (10.0f/150.0f)         // ALPHA_V*M
#define CU_CONST  0.9f                   // (1-ALPHA_U)
#define AU_CONST  0.1f                   // ALPHA_U

typedef __attribute__((ext_vector_type(8))) short short8;   // 8 bf16 = 4 VGPRs
typedef __attribute__((ext_vector_type(4))) float floatx4;

__device__ __forceinline__ unsigned short f2bf(float f) {
    union { float f; unsigned u; } x; x.f = f;
    unsigned r = x.u + 0x7fffu + ((x.u >> 16) & 1u);
    return (unsigned short)(r >> 16);
}

// ---------------------------------------------------------------------------
// Single fused pack: x,u -> Abf[8192][3072]; win,wr -> Wbf[2048][3072], bf16 RNE.
// (R3 post-mortem: pack ~60us incl. launch, near its BW floor — keep it.)
// ---------------------------------------------------------------------------
#define N4_X   ((B_DIM * D_IN)  / 4)
#define N4_U   ((B_DIM * H_DIM) / 4)
#define N4_WIN ((H_DIM * D_IN)  / 4)
#define N4_WR  ((H_DIM * H_DIM) / 4)
#define N4_TOT (N4_X + N4_U + N4_WIN + N4_WR)

__global__ __launch_bounds__(256)
void pack_all(const float4* __restrict__ x, const float4* __restrict__ u,
              const float4* __restrict__ win, const float4* __restrict__ wr,
              unsigned short* __restrict__ Abf, unsigned short* __restrict__ Wbf) {
    int i = blockIdx.x * 256 + threadIdx.x;
    const float4* src; unsigned short* dst; int shift, mask, coloff;
    if (i < N4_X)                    { src = x;   dst = Abf; shift = 10; mask = 1023; coloff = 0;    }
    else if (i < N4_X + N4_U)        { i -= N4_X; src = u;   dst = Abf; shift = 11; mask = 2047; coloff = D_IN; }
    else if (i < N4_X + N4_U + N4_WIN){ i -= N4_X + N4_U; src = win; dst = Wbf; shift = 10; mask = 1023; coloff = 0; }
    else                             { i -= N4_X + N4_U + N4_WIN; src = wr; dst = Wbf; shift = 11; mask = 2047; coloff = D_IN; }
    int idx = i << 2;
    int r = idx >> shift;
    int c = idx & mask;
    float4 f = src[i];
    ushort4 o;
    o.x = f2bf(f.x); o.y = f2bf(f.y); o.z = f2bf(f.z); o.w = f2bf(f.w);
    *(ushort4*)(dst + (size_t)r * K_DIM + coloff + c) = o;
}

// ---------------------------------------------------------------------------
// Fused GEMM: C = A(8192x3072) * Wc(2048x3072)^T, bf16 in, fp32 acc.
// R2 structure (global_load_lds staging) + BK=64: half the barrier drains,
// 32 MFMA per barrier pair. 8-slot swizzle keeps ds_read_b128 conflict-free.
// ---------------------------------------------------------------------------
#define GLOAD_LDS16(gp, lp)                                                          \
    __builtin_amdgcn_global_load_lds(                                                \
        (const __attribute__((address_space(1))) unsigned int*)(gp),                 \
        (__attribute__((address_space(3))) unsigned int*)(lp), 16, 0, 0)

#define BK 64
#define ES_STRIDE 68
#define ES_REGION (16 * ES_STRIDE)          // 1088 floats
#define SMEM_BYTES (8 * ES_REGION * 4)      // 34816 B >= As+Bs (32768 B)

__global__ __launch_bounds__(256, 4)
void gemm_fused(const unsigned short* __restrict__ A,   // [8192][3072] bf16
                const unsigned short* __restrict__ Wc,  // [2048][3072] bf16
                const float* __restrict__ u_in,         // [8192][2048]
                const float* __restrict__ v_in,         // [8192][2048]
                const float* __restrict__ bias,         // [2048]
                float* __restrict__ out)                // [u_new | v_new]
{
    __shared__ __align__(16) unsigned char smem_raw[SMEM_BYTES];
    unsigned short* As = (unsigned short*)smem_raw;        // 128 x 64 bf16 = 16 KB
    unsigned short* Bs = As + 128 * BK;                    // 16 KB
    float* Esf = (float*)smem_raw;                         // epilogue scratch (aliases)

    const int tid  = threadIdx.x;
    const int wave = tid >> 6;
    const int lane = tid & 63;

    // XCD swizzle: consecutive blockIdx round-robin XCDs; contiguous bm band
    // per XCD so co-resident blocks share A rows in L2.
    const int bid = blockIdx.x;
    const int wid = ((bid & 7) << 7) | (bid >> 3);
    const int bm = wid >> 4;     // 0..63
    const int bn = wid & 15;     // 0..15

    // --- staging: wave stages rows [wave*32, wave*32+32), 4 chunks of 8 rows
    // per matrix. Chunk = 8 rows x 128 B; lane l -> row l>>3, slot l&7.
    // Swizzle: slot s of row r holds k-group (s - r&7)&7; row&7 == l>>3 here.
    const int srow = lane >> 3;                       // 0..7
    const int grp  = ((lane & 7) - srow) & 7;         // k-group this lane carries
    const unsigned short* Ag = A  + (size_t)(bm * 128 + wave * 32 + srow) * K_DIM + grp * 8;
    const unsigned short* Bg = Wc + (size_t)(bn * 128 + wave * 32 + srow) * K_DIM + grp * 8;
    unsigned short* AsW = As + wave * 32 * BK;        // 2048 shorts per wave
    unsigned short* BsW = Bs + wave * 32 * BK;

    // --- compute-side fragment addressing (matches swizzle)
    const int wm = (wave >> 1) * 64;
    const int wn = (wave & 1) * 64;
    const int frow = lane & 15;
    const int g    = lane >> 4;          // quad k-group 0..3
    const int rot  = frow & 7;           // row rotation

    floatx4 acc[4][4] = {};

    for (int k0 = 0; k0 < K_DIM; k0 += BK) {
#pragma unroll
        for (int c = 0; c < 4; c++) {
            GLOAD_LDS16(Ag + (size_t)c * 8 * K_DIM + k0, AsW + c * 512);
            GLOAD_LDS16(Bg + (size_t)c * 8 * K_DIM + k0, BsW + c * 512);
        }
        __syncthreads();

#pragma unroll
        for (int s = 0; s < 2; s++) {
            const int swz = (((s << 2) + g + rot) & 7) * 8;
            short8 af[4], bfr[4];
#pragma unroll
            for (int i = 0; i < 4; i++)
                af[i] = *(const short8*)&As[(wm + i * 16 + frow) * BK + swz];
#pragma unroll
            for (int j = 0; j < 4; j++)
                bfr[j] = *(const short8*)&Bs[(wn + j * 16 + frow) * BK + swz];

#pragma unroll
            for (int i = 0; i < 4; i++)
#pragma unroll
                for (int j = 0; j < 4; j++)
                    acc[i][j] = __builtin_amdgcn_mfma_f32_16x16x32_bf16(
                        af[i], bfr[j], acc[i][j], 0, 0, 0);
        }
        __syncthreads();
    }

    // --- epilogue: transpose each 16x64 i-slice through LDS, then float4 I/O.
    // C/D layout: col = lane&15, row = (lane>>4)*4 + reg.
    const int q   = lane >> 4;
    const int c16 = lane & 15;
    const int rbase = q * 4;
    const int colg = bn * 128 + wn + c16 * 4;
    const float4 b4 = *(const float4*)&bias[colg];
    const size_t outV = (size_t)B_DIM * H_DIM;

#pragma unroll
    for (int i = 0; i < 4; i++) {
        float* Es = Esf + (wave * 2 + (i & 1)) * ES_REGION;
#pragma unroll
        for (int j = 0; j < 4; j++)
#pragma unroll
            for (int r = 0; r < 4; r++)
                Es[(rbase + r) * ES_STRIDE + j * 16 + c16] = acc[i][j][r];
#pragma unroll
        for (int rg = 0; rg < 4; rg++) {
            const int rloc = rg * 4 + q;
            const float4 a4 = *(const float4*)&Es[rloc * ES_STRIDE + c16 * 4];
            const size_t idx = (size_t)(bm * 128 + wm + i * 16 + rloc) * H_DIM + colg;
            const float4 u4 = *(const float4*)&u_in[idx];
            const float4 v4 = *(const float4*)&v_in[idx];
            float4 vn, un;
            vn.x = fmaxf(CV_CONST * v4.x + CUV_CONST * u4.x, 0.0f);
            vn.y = fmaxf(CV_CONST * v4.y + CUV_CONST * u4.y, 0.0f);
            vn.z = fmaxf(CV_CONST * v4.z + CUV_CONST * u4.z, 0.0f);
            vn.w = fmaxf(CV_CONST * v4.w + CUV_CONST * u4.w, 0.0f);
            un.x = fmaxf(CU_CONST * u4.x + AU_CONST * (a4.x + b4.x - vn.x), 0.0f);
            un.y = fmaxf(CU_CONST * u4.y + AU_CONST * (a4.y + b4.y - vn.y), 0.0f);
            un.z = fmaxf(CU_CONST * u4.z + AU_CONST * (a4.z + b4.z - vn.z), 0.0f);
            un.w = fmaxf(CU_CONST * u4.w + AU_CONST * (a4.w + b4.w - vn.w), 0.0f);
            *(float4*)&out[idx]        = un;
            *(float4*)&out[outV + idx] = vn;
        }
    }
}

// ---------------------------------------------------------------------------
extern "C" void kernel_launch(void* const* d_in, const int* in_sizes, int n_in,
                              void* d_out, int out_size, void* d_ws, size_t ws_size,
                              hipStream_t stream) {
    const float* x    = (const float*)d_in[0];
    const float* u    = (const float*)d_in[1];
    const float* v    = (const float*)d_in[2];
    const float* win  = (const float*)d_in[3];
    const float* wr   = (const float*)d_in[4];
    const float* bias = (const float*)d_in[5];
    float* out = (float*)d_out;

    unsigned short* Abf = (unsigned short*)d_ws;
    unsigned short* Wbf = Abf + (size_t)B_DIM * K_DIM;

    pack_all<<<N4_TOT / 256, 256, 0, stream>>>(
        (const float4*)x, (const float4*)u, (const float4*)win, (const float4*)wr,
        Abf, Wbf);

    gemm_fused<<<1024, 256, 0, stream>>>(Abf, Wbf, u, v, bias, out);
}